// Round 15
// baseline (78.038 us; speedup 1.0000x reference)
//
#include <hip/hip_runtime.h>
#include <math.h>

// PCEN v11 = v10 (62.0us champion: full-row lane mapping, NT stores,
// chained spans, prefetch-across-raw-barrier) with ONE change: SPC_ 4 -> 2
// (chain 512 steps, TSPLIT 16 -> grid 1024 = 4 blocks/CU = 20 waves/CU,
// double the TLP). Halo fraction rises to 50% but halo reads are L3-hot
// (R14: steady-state FETCH 97MB << 168MB unique).
//
// M[t] = a*M[t-1] + s*x[t], M[0]=x[0]
// out  = sqrt(x*(M+eps)^-0.98 + 2) - sqrt(2)

#define B_      64
#define T_      8192
#define F4_     20                // 80 f32 = 20 float4
#define SPB_    20                // f4 per block = ALL of them (full rows)
#define CPB_    16                // chunks per span
#define LCH_    16                // steps per chunk
#define SPAN_   (CPB_ * LCH_)     // 256
#define SPC_    2                 // spans per chain  (v10: 4)
#define CHAIN_  (SPC_ * SPAN_)    // 512
#define TSPLIT_ (T_ / CHAIN_)     // 16 chains per seq
#define NG_     B_                // -> grid 1024
#define THR_    (SPB_ * CPB_)     // 320 threads = 5 waves
#define SA_     0.025f
#define AA_     0.975f
#define A8_     0.81665182f       // 0.975^8
#define A16_    0.66692016f       // 0.975^16
#define A16S_   26.676807f        // A16_/SA_ (chunk-0 exact fix, u-space)

typedef float f4v __attribute__((ext_vector_type(4)));

__device__ __forceinline__ float pcen1(float xv, float m) {
    float l = __builtin_amdgcn_logf(m + 1e-6f);        // v_log_f32 (log2)
    float g = __builtin_amdgcn_exp2f(-0.98f * l);      // (m+eps)^(-alpha)
    return __builtin_amdgcn_sqrtf(fmaf(xv, g, 2.0f)) - 1.4142135623730951f;
}

__device__ __forceinline__ float4 pcen4(float4 xv, float4 m) {
    float4 o;
    o.x = pcen1(xv.x, m.x);
    o.y = pcen1(xv.y, m.y);
    o.z = pcen1(xv.z, m.z);
    o.w = pcen1(xv.w, m.w);
    return o;
}

// d = c*d + v
__device__ __forceinline__ void hstep(float4& d, float c, const float4 v) {
    d.x = fmaf(c, d.x, v.x);
    d.y = fmaf(c, d.y, v.y);
    d.z = fmaf(c, d.z, v.z);
    d.w = fmaf(c, d.w, v.w);
}

// d += c*v
__device__ __forceinline__ void faxpy(float4& d, float c, const float4 v) {
    d.x = fmaf(c, v.x, d.x);
    d.y = fmaf(c, v.y, d.y);
    d.z = fmaf(c, v.z, d.z);
    d.w = fmaf(c, v.w, d.w);
}

// m = a*m + s*x
__device__ __forceinline__ void ema4(float4& m, const float4 xv) {
    m.x = fmaf(AA_, m.x, SA_ * xv.x);
    m.y = fmaf(AA_, m.y, SA_ * xv.y);
    m.z = fmaf(AA_, m.z, SA_ * xv.z);
    m.w = fmaf(AA_, m.w, SA_ * xv.w);
}

// lgkmcnt-only barrier: LDS visibility without draining vmcnt (prefetch
// stays in flight across the barrier).
__device__ __forceinline__ void lds_barrier() {
    asm volatile("s_waitcnt lgkmcnt(0)" ::: "memory");
    __builtin_amdgcn_s_barrier();
}

// One span: partial -> LDS(cur half), prefetch next span, barrier,
// circular Horner carry, barrier, produce + NT stores.
// PB = prev-half base row (16 or 0); cur half = PB^16.
template <int PB, bool PREFETCH>
__device__ __forceinline__ void one_span(
    float4 (&cur)[LCH_], float4 (&nxt)[LCH_],
    const float4* __restrict__ xnext,
    const int s, const int lc,
    const float fixP, const float fixM,
    float4 (*P)[SPB_],
    float4* __restrict__ op)
{
    // ---- u-space partial of cur chunk (two 8-chains) ----
    float4 u0 = make_float4(0.f, 0.f, 0.f, 0.f);
    float4 u1 = make_float4(0.f, 0.f, 0.f, 0.f);
    #pragma unroll
    for (int j = 0; j < 8; ++j) {
        hstep(u0, AA_, cur[j]);
        hstep(u1, AA_, cur[j + 8]);
    }
    float4 pu = u1;
    faxpy(pu, A8_, u0);
    faxpy(pu, fixP, cur[0]);               // chunk-0 exact fix (usually 0)
    P[(PB ^ 16) + lc][s] = pu;

    // ---- prefetch next span (in flight across the barrier) ----
    if (PREFETCH) {
        #pragma unroll
        for (int j = 0; j < LCH_; ++j) nxt[j] = xnext[(size_t)j * F4_];
    }

    lds_barrier();

    // ---- carry: circular 16-term Horner, rows (PB+lc+k)&31, oldest->newest
    float4 u = P[(PB + lc) & 31][s];
    #pragma unroll
    for (int k = 1; k < CPB_; ++k) hstep(u, A16_, P[(PB + lc + k) & 31][s]);

    lds_barrier();                         // reads done before next overwrite

    float4 m;
    m.x = SA_ * u.x; m.y = SA_ * u.y; m.z = SA_ * u.z; m.w = SA_ * u.w;

    // ---- produce: EMA + pcen, nontemporal stores (R13-validated) ----
    ema4(m, cur[0]);
    faxpy(m, fixM, cur[0]);                // global t=0: m = x[0] exactly
    {
        float4 v = pcen4(cur[0], m);
        __builtin_nontemporal_store(*(f4v*)&v, (f4v*)op);
    }
    #pragma unroll
    for (int j = 1; j < LCH_; ++j) {
        ema4(m, cur[j]);
        float4 v = pcen4(cur[j], m);
        __builtin_nontemporal_store(*(f4v*)&v, (f4v*)(op + (size_t)j * F4_));
    }
}

__global__ void __launch_bounds__(THR_, 4)
pcen_chain(const float4* __restrict__ x4, float4* __restrict__ o4) {
    __shared__ float4 P[2 * CPB_][SPB_];   // 32 rows x 20, circular halves

    const int tid = threadIdx.x;
    const int s   = tid % SPB_;            // f4 index 0..19 (full row)
    const int lc  = tid / SPB_;            // chunk 0..15

    const int b     = blockIdx.x % NG_;    // chain-major: time walks together
    const int chain = blockIdx.x / NG_;

    const float4* xbase = x4 + (size_t)b * ((size_t)T_ * F4_) + s;
    float4*       obase = o4 + (size_t)b * ((size_t)T_ * F4_) + s;

    const int t00 = chain * CHAIN_ + lc * LCH_;   // span-0 chunk start

    float4 xA[LCH_], xB[LCH_];

    // span-0 loads
    const float4* pc = xbase + (size_t)t00 * F4_;
    #pragma unroll
    for (int j = 0; j < LCH_; ++j) xA[j] = pc[(size_t)j * F4_];

    // halo partials -> prev half (rows 16..31); zeros for chain 0
    if (chain > 0) {                       // block-uniform branch
        const float4* ph = pc - (size_t)SPAN_ * F4_;
        #pragma unroll
        for (int j = 0; j < LCH_; ++j) xB[j] = ph[(size_t)j * F4_];
        float4 u0 = make_float4(0.f, 0.f, 0.f, 0.f);
        float4 u1 = make_float4(0.f, 0.f, 0.f, 0.f);
        #pragma unroll
        for (int j = 0; j < 8; ++j) {
            hstep(u0, AA_, xB[j]);
            hstep(u1, AA_, xB[j + 8]);
        }
        float4 hu = u1;
        faxpy(hu, A8_, u0);
        P[CPB_ + lc][s] = hu;
    } else {
        P[CPB_ + lc][s] = make_float4(0.f, 0.f, 0.f, 0.f);
    }

    const bool  c0   = (chain == 0 && lc == 0);
    const float fixP = c0 ? A16S_ : 0.0f;
    const float fixM = c0 ? AA_   : 0.0f;

    float4*       op = obase + (size_t)t00 * F4_;
    const size_t  so = (size_t)SPAN_ * F4_;

    one_span<16, true >(xA, xB, pc + so, s, lc, fixP, fixM, P, op);
    one_span< 0, false>(xB, xA, pc,      s, lc, 0.f,  0.f,  P, op + so);
}

extern "C" void kernel_launch(void* const* d_in, const int* in_sizes, int n_in,
                              void* d_out, int out_size, void* d_ws, size_t ws_size,
                              hipStream_t stream) {
    const float4* x4 = (const float4*)d_in[0];
    float4*       o4 = (float4*)d_out;

    pcen_chain<<<dim3(NG_ * TSPLIT_), dim3(THR_), 0, stream>>>(x4, o4);
}

// Round 16
// 60.570 us; speedup vs baseline: 1.2884x; 1.2884x over previous
//
#include <hip/hip_runtime.h>
#include <math.h>

// PCEN v12 = v14 champion (62.0us: full-row lanes, NT stores, chained spans,
// prefetch-across-raw-barrier) with ONE change: SPC_ 4 -> 8 (chain 2048,
// grid 256 = 1 block/CU). Halves halo re-read to 12.5% -> fabric bytes
// 385 -> 364 MB; v15 proved the kernel is at the ~6.2 TB/s aggregate
// roofline, so bytes are the only lever left.
//
// M[t] = a*M[t-1] + s*x[t], M[0]=x[0]
// out  = sqrt(x*(M+eps)^-0.98 + 2) - sqrt(2)

#define B_      64
#define T_      8192
#define F4_     20                // 80 f32 = 20 float4
#define SPB_    20                // f4 per block = ALL of them (full rows)
#define CPB_    16                // chunks per span
#define LCH_    16                // steps per chunk
#define SPAN_   (CPB_ * LCH_)     // 256
#define SPC_    8                 // spans per chain  (v14: 4)
#define CHAIN_  (SPC_ * SPAN_)    // 2048
#define TSPLIT_ (T_ / CHAIN_)     // 4 chains per seq
#define NG_     B_                // -> grid 256
#define THR_    (SPB_ * CPB_)     // 320 threads = 5 waves
#define SA_     0.025f
#define AA_     0.975f
#define A8_     0.81665182f       // 0.975^8
#define A16_    0.66692016f       // 0.975^16
#define A16S_   26.676807f        // A16_/SA_ (chunk-0 exact fix, u-space)

typedef float f4v __attribute__((ext_vector_type(4)));

__device__ __forceinline__ float pcen1(float xv, float m) {
    float l = __builtin_amdgcn_logf(m + 1e-6f);        // v_log_f32 (log2)
    float g = __builtin_amdgcn_exp2f(-0.98f * l);      // (m+eps)^(-alpha)
    return __builtin_amdgcn_sqrtf(fmaf(xv, g, 2.0f)) - 1.4142135623730951f;
}

__device__ __forceinline__ float4 pcen4(float4 xv, float4 m) {
    float4 o;
    o.x = pcen1(xv.x, m.x);
    o.y = pcen1(xv.y, m.y);
    o.z = pcen1(xv.z, m.z);
    o.w = pcen1(xv.w, m.w);
    return o;
}

// d = c*d + v
__device__ __forceinline__ void hstep(float4& d, float c, const float4 v) {
    d.x = fmaf(c, d.x, v.x);
    d.y = fmaf(c, d.y, v.y);
    d.z = fmaf(c, d.z, v.z);
    d.w = fmaf(c, d.w, v.w);
}

// d += c*v
__device__ __forceinline__ void faxpy(float4& d, float c, const float4 v) {
    d.x = fmaf(c, v.x, d.x);
    d.y = fmaf(c, v.y, d.y);
    d.z = fmaf(c, v.z, d.z);
    d.w = fmaf(c, v.w, d.w);
}

// m = a*m + s*x
__device__ __forceinline__ void ema4(float4& m, const float4 xv) {
    m.x = fmaf(AA_, m.x, SA_ * xv.x);
    m.y = fmaf(AA_, m.y, SA_ * xv.y);
    m.z = fmaf(AA_, m.z, SA_ * xv.z);
    m.w = fmaf(AA_, m.w, SA_ * xv.w);
}

// lgkmcnt-only barrier: LDS visibility without draining vmcnt (prefetch
// stays in flight across the barrier).
__device__ __forceinline__ void lds_barrier() {
    asm volatile("s_waitcnt lgkmcnt(0)" ::: "memory");
    __builtin_amdgcn_s_barrier();
}

// One span: partial -> LDS(cur half), prefetch next span, barrier,
// circular Horner carry, barrier, produce + NT stores.
// PB = prev-half base row (16 or 0); cur half = PB^16.
template <int PB, bool PREFETCH>
__device__ __forceinline__ void one_span(
    float4 (&cur)[LCH_], float4 (&nxt)[LCH_],
    const float4* __restrict__ xnext,
    const int s, const int lc,
    const float fixP, const float fixM,
    float4 (*P)[SPB_],
    float4* __restrict__ op)
{
    // ---- u-space partial of cur chunk (two 8-chains) ----
    float4 u0 = make_float4(0.f, 0.f, 0.f, 0.f);
    float4 u1 = make_float4(0.f, 0.f, 0.f, 0.f);
    #pragma unroll
    for (int j = 0; j < 8; ++j) {
        hstep(u0, AA_, cur[j]);
        hstep(u1, AA_, cur[j + 8]);
    }
    float4 pu = u1;
    faxpy(pu, A8_, u0);
    faxpy(pu, fixP, cur[0]);               // chunk-0 exact fix (usually 0)
    P[(PB ^ 16) + lc][s] = pu;

    // ---- prefetch next span (in flight across the barrier) ----
    if (PREFETCH) {
        #pragma unroll
        for (int j = 0; j < LCH_; ++j) nxt[j] = xnext[(size_t)j * F4_];
    }

    lds_barrier();

    // ---- carry: circular 16-term Horner, rows (PB+lc+k)&31, oldest->newest
    float4 u = P[(PB + lc) & 31][s];
    #pragma unroll
    for (int k = 1; k < CPB_; ++k) hstep(u, A16_, P[(PB + lc + k) & 31][s]);

    lds_barrier();                         // reads done before next overwrite

    float4 m;
    m.x = SA_ * u.x; m.y = SA_ * u.y; m.z = SA_ * u.z; m.w = SA_ * u.w;

    // ---- produce: EMA + pcen, nontemporal stores (R13-validated) ----
    ema4(m, cur[0]);
    faxpy(m, fixM, cur[0]);                // global t=0: m = x[0] exactly
    {
        float4 v = pcen4(cur[0], m);
        __builtin_nontemporal_store(*(f4v*)&v, (f4v*)op);
    }
    #pragma unroll
    for (int j = 1; j < LCH_; ++j) {
        ema4(m, cur[j]);
        float4 v = pcen4(cur[j], m);
        __builtin_nontemporal_store(*(f4v*)&v, (f4v*)(op + (size_t)j * F4_));
    }
}

__global__ void __launch_bounds__(THR_, 2)
pcen_chain(const float4* __restrict__ x4, float4* __restrict__ o4) {
    __shared__ float4 P[2 * CPB_][SPB_];   // 32 rows x 20, circular halves

    const int tid = threadIdx.x;
    const int s   = tid % SPB_;            // f4 index 0..19 (full row)
    const int lc  = tid / SPB_;            // chunk 0..15

    const int b     = blockIdx.x % NG_;    // chain-major: time walks together
    const int chain = blockIdx.x / NG_;

    const float4* xbase = x4 + (size_t)b * ((size_t)T_ * F4_) + s;
    float4*       obase = o4 + (size_t)b * ((size_t)T_ * F4_) + s;

    const int t00 = chain * CHAIN_ + lc * LCH_;   // span-0 chunk start

    float4 xA[LCH_], xB[LCH_];

    // span-0 loads
    const float4* pc = xbase + (size_t)t00 * F4_;
    #pragma unroll
    for (int j = 0; j < LCH_; ++j) xA[j] = pc[(size_t)j * F4_];

    // halo partials -> prev half (rows 16..31); zeros for chain 0
    if (chain > 0) {                       // block-uniform branch
        const float4* ph = pc - (size_t)SPAN_ * F4_;
        #pragma unroll
        for (int j = 0; j < LCH_; ++j) xB[j] = ph[(size_t)j * F4_];
        float4 u0 = make_float4(0.f, 0.f, 0.f, 0.f);
        float4 u1 = make_float4(0.f, 0.f, 0.f, 0.f);
        #pragma unroll
        for (int j = 0; j < 8; ++j) {
            hstep(u0, AA_, xB[j]);
            hstep(u1, AA_, xB[j + 8]);
        }
        float4 hu = u1;
        faxpy(hu, A8_, u0);
        P[CPB_ + lc][s] = hu;
    } else {
        P[CPB_ + lc][s] = make_float4(0.f, 0.f, 0.f, 0.f);
    }

    const bool  c0   = (chain == 0 && lc == 0);
    const float fixP = c0 ? A16S_ : 0.0f;
    const float fixM = c0 ? AA_   : 0.0f;

    float4*       op = obase + (size_t)t00 * F4_;
    const size_t  so = (size_t)SPAN_ * F4_;

    one_span<16, true >(xA, xB, pc +     so, s, lc, fixP, fixM, P, op);
    one_span< 0, true >(xB, xA, pc + 2 * so, s, lc, 0.f,  0.f,  P, op +     so);
    one_span<16, true >(xA, xB, pc + 3 * so, s, lc, 0.f,  0.f,  P, op + 2 * so);
    one_span< 0, true >(xB, xA, pc + 4 * so, s, lc, 0.f,  0.f,  P, op + 3 * so);
    one_span<16, true >(xA, xB, pc + 5 * so, s, lc, 0.f,  0.f,  P, op + 4 * so);
    one_span< 0, true >(xB, xA, pc + 6 * so, s, lc, 0.f,  0.f,  P, op + 5 * so);
    one_span<16, true >(xA, xB, pc + 7 * so, s, lc, 0.f,  0.f,  P, op + 6 * so);
    one_span< 0, false>(xB, xA, pc,          s, lc, 0.f,  0.f,  P, op + 7 * so);
}

extern "C" void kernel_launch(void* const* d_in, const int* in_sizes, int n_in,
                              void* d_out, int out_size, void* d_ws, size_t ws_size,
                              hipStream_t stream) {
    const float4* x4 = (const float4*)d_in[0];
    float4*       o4 = (float4*)d_out;

    pcen_chain<<<dim3(NG_ * TSPLIT_), dim3(THR_), 0, stream>>>(x4, o4);
}